// Round 7
// baseline (176.152 us; speedup 1.0000x reference)
//
#include <hip/hip_runtime.h>

#define THREADS 256

typedef __attribute__((ext_vector_type(8))) short bf16x8;
typedef __attribute__((ext_vector_type(4))) float f32x4;

// fp32 -> bf16 with round-to-nearest-even (matches HW convert)
__device__ inline unsigned short f2bf(float f) {
    union { float f; unsigned int u; } v; v.f = f;
    unsigned int r = v.u + 0x7fffu + ((v.u >> 16) & 1u);
    return (unsigned short)(r >> 16);
}

// ---------------------------------------------------------------------------
// Kernel A: in-side contraction  x[N,4096] -> u3b[N,512] (bf16)
//   (EXACT round-0 proven version, ~21 us. FROZEN.)
// ---------------------------------------------------------------------------
__global__ __launch_bounds__(THREADS) void k_in_contract(
    const float* __restrict__ x,
    const float* __restrict__ f3, const float* __restrict__ f4,
    const float* __restrict__ f5,
    unsigned short* __restrict__ u3b, int N)
{
    const int n = blockIdx.x;
    const int t = threadIdx.x;

    __shared__ float fs[256];        // f3 [0..128) | f4 [128..256)
    __shared__ float u1s[256 * 9];   // [de][n6], pad 9 -> 2-way max
    __shared__ float u2s[128 * 9];   // [d*8+m][n6], pad 9

    if (t < 128) { fs[t] = f3[t]; fs[128 + t] = f4[t]; }

    float xv[16];
    {
        const float4* xr = (const float4*)(x + (size_t)n * 4096 + t * 16);
        float4 a0 = xr[0], a1 = xr[1], a2 = xr[2], a3 = xr[3];
        xv[0]=a0.x; xv[1]=a0.y; xv[2]=a0.z; xv[3]=a0.w;
        xv[4]=a1.x; xv[5]=a1.y; xv[6]=a1.z; xv[7]=a1.w;
        xv[8]=a2.x; xv[9]=a2.y; xv[10]=a2.z; xv[11]=a2.w;
        xv[12]=a3.x; xv[13]=a3.y; xv[14]=a3.z; xv[15]=a3.w;
    }

    float acc8[8];
    #pragma unroll
    for (int q = 0; q < 8; ++q) acc8[q] = 0.f;
    #pragma unroll
    for (int f = 0; f < 16; ++f) {
        const float xf = xv[f];
        #pragma unroll
        for (int n6 = 0; n6 < 8; ++n6)
            acc8[n6] = fmaf(xf, f5[f*8 + n6], acc8[n6]);
    }
    __syncthreads();
    #pragma unroll
    for (int n6 = 0; n6 < 8; ++n6) u1s[t*9 + n6] = acc8[n6];
    __syncthreads();

    {
        const int d = t >> 4, m = (t >> 1) & 7, h = t & 1;
        float fr[16];
        #pragma unroll
        for (int e = 0; e < 16; ++e) fr[e] = fs[128 + e*8 + m];
        float a4[4] = {0.f, 0.f, 0.f, 0.f};
        #pragma unroll
        for (int e = 0; e < 16; ++e) {
            const int base = (d*16 + e)*9 + h*4;
            #pragma unroll
            for (int q = 0; q < 4; ++q)
                a4[q] = fmaf(u1s[base + q], fr[e], a4[q]);
        }
        #pragma unroll
        for (int q = 0; q < 4; ++q) u2s[(d*8 + m)*9 + h*4 + q] = a4[q];
    }
    __syncthreads();

    {
        const int l = t >> 5, m = (t >> 2) & 7, h = t & 3;
        float fr[16];
        #pragma unroll
        for (int d = 0; d < 16; ++d) fr[d] = fs[d*8 + l];
        float a2[2] = {0.f, 0.f};
        #pragma unroll
        for (int d = 0; d < 16; ++d) {
            const int base = (d*8 + m)*9 + h*2;
            a2[0] = fmaf(u2s[base],     fr[d], a2[0]);
            a2[1] = fmaf(u2s[base + 1], fr[d], a2[1]);
        }
        unsigned int pk = (unsigned int)f2bf(a2[0]) |
                          ((unsigned int)f2bf(a2[1]) << 16);
        ((unsigned int*)u3b)[(size_t)n * 256 + t] = pk;
    }
}

// ---------------------------------------------------------------------------
// core fp32 [512,512] -> bf16. (FROZEN)
// ---------------------------------------------------------------------------
__global__ __launch_bounds__(THREADS) void k_convert_core(
    const float* __restrict__ core, unsigned short* __restrict__ coreb)
{
    const int i = blockIdx.x * THREADS + threadIdx.x;
    float4 c = ((const float4*)core)[i];
    ushort4 o;
    o.x = f2bf(c.x); o.y = f2bf(c.y); o.z = f2bf(c.z); o.w = f2bf(c.w);
    ((ushort4*)coreb)[i] = o;
}

// ---------------------------------------------------------------------------
// Kernel B (v3): MFMA GEMM, occupancy-first + B shared via L1.
//   (EXACT round-5 version — ledger-measured at ~21.6 us there, vs ~40 us
//    for the 512-block round-0 gemm which was 2 waves/SIMD latency-bound.)
//   v[n,p] = sum_q u3[n,q] * core[p,q]
//   Wave tile 16x16, K=512 unrolled. Block = 4 waves: SAME p-tile (B-frag
//   addresses identical across waves -> L1 broadcast), consecutive m-tiles.
//   Grid (4096/64, 512/16) = (64,32) = 2048 blocks = 8 blocks/CU;
//   launch_bounds(256,8) -> 8 waves/SIMD.
//   A-frag: lane = row m0+(lane&15), k=(lane>>4)*8+j     [m89/m91]
//   C/D:    col = lane&15, row = (lane>>4)*4 + reg
// ---------------------------------------------------------------------------
__global__ __launch_bounds__(THREADS, 8) void k_core_gemm3(
    const unsigned short* __restrict__ u3b,
    const unsigned short* __restrict__ coreb,
    float* __restrict__ v, int N)
{
    const int t    = threadIdx.x;
    const int lane = t & 63;
    const int wave = t >> 6;
    const int m0 = blockIdx.x * 64 + wave * 16;
    const int p0 = blockIdx.y * 16;
    const int lr = lane & 15;
    const int lq = lane >> 4;

    const unsigned short* ap = u3b   + (size_t)(m0 + lr) * 512 + lq * 8;
    const unsigned short* bp = coreb + (size_t)(p0 + lr) * 512 + lq * 8;

    f32x4 acc = {0.f, 0.f, 0.f, 0.f};
    #pragma unroll
    for (int kt = 0; kt < 16; ++kt) {
        bf16x8 a = *(const bf16x8*)(ap + kt * 32);
        bf16x8 b = *(const bf16x8*)(bp + kt * 32);
        acc = __builtin_amdgcn_mfma_f32_16x16x32_bf16(a, b, acc, 0, 0, 0);
    }

    const int row = m0 + lq * 4;
    const int col = p0 + lr;
    #pragma unroll
    for (int r = 0; r < 4; ++r)
        v[(size_t)(row + r) * 512 + col] = acc[r];
}

// ---------------------------------------------------------------------------
// Kernel C: out-side expansion, block-per-row, minus dead w2s stage.
//   (EXACT round-4 version — ledger-measured at ~8 us there; the best
//    measured expansion structure. FROZEN.)
// ---------------------------------------------------------------------------
__global__ __launch_bounds__(THREADS) void k_out_expand(
    const float* __restrict__ v,
    const float* __restrict__ f0, const float* __restrict__ f1,
    const float* __restrict__ f2, const float* __restrict__ bias,
    float* __restrict__ y, int N)
{
    const int n = blockIdx.x;
    const int t = threadIdx.x;

    __shared__ float fs[256];        // f0 [0..128) | f1 [128..256)
    __shared__ float vs[512];
    __shared__ float w1s[128 * 9];   // [a*8+j][k], pad 9

    if (t < 128) { fs[t] = f0[t]; fs[128 + t] = f1[t]; }
    if (t < 128) ((float4*)vs)[t] = ((const float4*)(v + (size_t)n*512))[t];
    __syncthreads();

    // w1 stage: thread -> (a = t>>4, j = (t>>1)&7, h = t&1), k = 4h..4h+3
    {
        const int a = t >> 4, j = (t >> 1) & 7, h = t & 1;
        float fr[8];
        #pragma unroll
        for (int i = 0; i < 8; ++i) fr[i] = fs[a*8 + i];
        float a4[4] = {0.f, 0.f, 0.f, 0.f};
        #pragma unroll
        for (int i = 0; i < 8; ++i) {
            const int base = i*64 + j*8 + h*4;
            #pragma unroll
            for (int q = 0; q < 4; ++q)
                a4[q] = fmaf(vs[base + q], fr[i], a4[q]);
        }
        #pragma unroll
        for (int q = 0; q < 4; ++q) w1s[(a*8 + j)*9 + h*4 + q] = a4[q];
    }
    __syncthreads();

    // w2 (in regs) + y stage: thread -> (a = t>>4, b = t&15), c = 0..15
    {
        const int a = t >> 4, b = t & 15;
        float fr[8];
        #pragma unroll
        for (int j = 0; j < 8; ++j) fr[j] = fs[128 + b*8 + j];
        float w2[8] = {0.f,0.f,0.f,0.f,0.f,0.f,0.f,0.f};
        #pragma unroll
        for (int j = 0; j < 8; ++j) {
            const int base = (a*8 + j)*9;
            const float fj = fr[j];
            #pragma unroll
            for (int k = 0; k < 8; ++k)
                w2[k] = fmaf(w1s[base + k], fj, w2[k]);
        }

        const int obase = a*256 + b*16;   // == t*16
        float4 b4[4];
        {
            const float4* bp = (const float4*)(bias + obase);
            b4[0] = bp[0]; b4[1] = bp[1]; b4[2] = bp[2]; b4[3] = bp[3];
        }
        float yv[16];
        #pragma unroll
        for (int q = 0; q < 4; ++q) {
            yv[q*4+0] = b4[q].x; yv[q*4+1] = b4[q].y;
            yv[q*4+2] = b4[q].z; yv[q*4+3] = b4[q].w;
        }
        #pragma unroll
        for (int c = 0; c < 16; ++c) {
            float s = yv[c];
            #pragma unroll
            for (int k = 0; k < 8; ++k)
                s = fmaf(w2[k], f2[c*8 + k], s);   // f2 lane-uniform -> s_load
            yv[c] = s;
        }
        float4* o = (float4*)(y + (size_t)n*4096 + obase);
        #pragma unroll
        for (int q = 0; q < 4; ++q)
            o[q] = make_float4(yv[q*4+0], yv[q*4+1], yv[q*4+2], yv[q*4+3]);
    }
}

// ---------------------------------------------------------------------------
extern "C" void kernel_launch(void* const* d_in, const int* in_sizes, int n_in,
                              void* d_out, int out_size, void* d_ws, size_t ws_size,
                              hipStream_t stream)
{
    const float* x    = (const float*)d_in[0];
    const float* core = (const float*)d_in[1];
    const float* f0   = (const float*)d_in[2];
    const float* f1   = (const float*)d_in[3];
    const float* f2   = (const float*)d_in[4];
    const float* f3   = (const float*)d_in[5];
    const float* f4   = (const float*)d_in[6];
    const float* f5   = (const float*)d_in[7];
    const float* bias = (const float*)d_in[8];
    float* y = (float*)d_out;

    const int N = in_sizes[0] / 4096;

    // workspace: u3b bf16 [N,512] (4MB) | coreb bf16 [512,512] (0.5MB)
    //          | v fp32 [N,512] (8MB)
    unsigned short* u3b   = (unsigned short*)d_ws;
    unsigned short* coreb = u3b + (size_t)N * 512;
    float*          v     = (float*)(coreb + 512 * 512);

    k_in_contract<<<N, THREADS, 0, stream>>>(x, f3, f4, f5, u3b, N);
    k_convert_core<<<256, THREADS, 0, stream>>>(core, coreb);
    dim3 gb(N / 64, 512 / 16);
    k_core_gemm3<<<gb, THREADS, 0, stream>>>(u3b, coreb, v, N);
    k_out_expand<<<N, THREADS, 0, stream>>>(v, f0, f1, f2, bias, y, N);
}

// Round 8
// 161.465 us; speedup vs baseline: 1.0910x; 1.0910x over previous
//
#include <hip/hip_runtime.h>

#define THREADS 256

typedef __attribute__((ext_vector_type(8))) short bf16x8;
typedef __attribute__((ext_vector_type(4))) float f32x4;

// fp32 -> bf16 with round-to-nearest-even (matches HW convert)
__device__ inline unsigned short f2bf(float f) {
    union { float f; unsigned int u; } v; v.f = f;
    unsigned int r = v.u + 0x7fffu + ((v.u >> 16) & 1u);
    return (unsigned short)(r >> 16);
}

// ---------------------------------------------------------------------------
// Kernel A: in-side contraction  x[N,4096] -> u3b[N,512] (bf16)
//   (EXACT round-0 proven version, ~21 us. FROZEN.)
// ---------------------------------------------------------------------------
__global__ __launch_bounds__(THREADS) void k_in_contract(
    const float* __restrict__ x,
    const float* __restrict__ f3, const float* __restrict__ f4,
    const float* __restrict__ f5,
    unsigned short* __restrict__ u3b, int N)
{
    const int n = blockIdx.x;
    const int t = threadIdx.x;

    __shared__ float fs[256];        // f3 [0..128) | f4 [128..256)
    __shared__ float u1s[256 * 9];   // [de][n6], pad 9 -> 2-way max
    __shared__ float u2s[128 * 9];   // [d*8+m][n6], pad 9

    if (t < 128) { fs[t] = f3[t]; fs[128 + t] = f4[t]; }

    float xv[16];
    {
        const float4* xr = (const float4*)(x + (size_t)n * 4096 + t * 16);
        float4 a0 = xr[0], a1 = xr[1], a2 = xr[2], a3 = xr[3];
        xv[0]=a0.x; xv[1]=a0.y; xv[2]=a0.z; xv[3]=a0.w;
        xv[4]=a1.x; xv[5]=a1.y; xv[6]=a1.z; xv[7]=a1.w;
        xv[8]=a2.x; xv[9]=a2.y; xv[10]=a2.z; xv[11]=a2.w;
        xv[12]=a3.x; xv[13]=a3.y; xv[14]=a3.z; xv[15]=a3.w;
    }

    float acc8[8];
    #pragma unroll
    for (int q = 0; q < 8; ++q) acc8[q] = 0.f;
    #pragma unroll
    for (int f = 0; f < 16; ++f) {
        const float xf = xv[f];
        #pragma unroll
        for (int n6 = 0; n6 < 8; ++n6)
            acc8[n6] = fmaf(xf, f5[f*8 + n6], acc8[n6]);
    }
    __syncthreads();
    #pragma unroll
    for (int n6 = 0; n6 < 8; ++n6) u1s[t*9 + n6] = acc8[n6];
    __syncthreads();

    {
        const int d = t >> 4, m = (t >> 1) & 7, h = t & 1;
        float fr[16];
        #pragma unroll
        for (int e = 0; e < 16; ++e) fr[e] = fs[128 + e*8 + m];
        float a4[4] = {0.f, 0.f, 0.f, 0.f};
        #pragma unroll
        for (int e = 0; e < 16; ++e) {
            const int base = (d*16 + e)*9 + h*4;
            #pragma unroll
            for (int q = 0; q < 4; ++q)
                a4[q] = fmaf(u1s[base + q], fr[e], a4[q]);
        }
        #pragma unroll
        for (int q = 0; q < 4; ++q) u2s[(d*8 + m)*9 + h*4 + q] = a4[q];
    }
    __syncthreads();

    {
        const int l = t >> 5, m = (t >> 2) & 7, h = t & 3;
        float fr[16];
        #pragma unroll
        for (int d = 0; d < 16; ++d) fr[d] = fs[d*8 + l];
        float a2[2] = {0.f, 0.f};
        #pragma unroll
        for (int d = 0; d < 16; ++d) {
            const int base = (d*8 + m)*9 + h*2;
            a2[0] = fmaf(u2s[base],     fr[d], a2[0]);
            a2[1] = fmaf(u2s[base + 1], fr[d], a2[1]);
        }
        unsigned int pk = (unsigned int)f2bf(a2[0]) |
                          ((unsigned int)f2bf(a2[1]) << 16);
        ((unsigned int*)u3b)[(size_t)n * 256 + t] = pk;
    }
}

// ---------------------------------------------------------------------------
// core fp32 [512,512] -> bf16. (FROZEN)
// ---------------------------------------------------------------------------
__global__ __launch_bounds__(THREADS) void k_convert_core(
    const float* __restrict__ core, unsigned short* __restrict__ coreb)
{
    const int i = blockIdx.x * THREADS + threadIdx.x;
    float4 c = ((const float4*)core)[i];
    ushort4 o;
    o.x = f2bf(c.x); o.y = f2bf(c.y); o.z = f2bf(c.z); o.w = f2bf(c.w);
    ((ushort4*)coreb)[i] = o;
}

// ---------------------------------------------------------------------------
// Kernel B: MFMA GEMM (EXACT round-0 proven version — ledger-resolved at
//   ~8.6 us, the FASTEST gemm measured; gemm3's 2048-block variant was
//   21.6 us from 4x B re-fetch. FROZEN.)
//   Wave tile 32x32 (2x2 of 16x16x32 bf16). Grid (32,16) = 512 blocks.
// ---------------------------------------------------------------------------
__global__ __launch_bounds__(THREADS) void k_core_gemm_mfma(
    const unsigned short* __restrict__ u3b,
    const unsigned short* __restrict__ coreb,
    float* __restrict__ v, int N)
{
    const int t    = threadIdx.x;
    const int lane = t & 63;
    const int wave = t >> 6;
    const int m0 = blockIdx.x * 128 + wave * 32;
    const int p0 = blockIdx.y * 32;
    const int lr = lane & 15;
    const int lq = lane >> 4;

    const unsigned short* aptr0 = u3b   + (size_t)(m0 + lr) * 512 + lq * 8;
    const unsigned short* aptr1 = aptr0 + 16 * 512;
    const unsigned short* bptr0 = coreb + (size_t)(p0 + lr) * 512 + lq * 8;
    const unsigned short* bptr1 = bptr0 + 16 * 512;

    f32x4 acc00 = {0.f,0.f,0.f,0.f}, acc01 = {0.f,0.f,0.f,0.f};
    f32x4 acc10 = {0.f,0.f,0.f,0.f}, acc11 = {0.f,0.f,0.f,0.f};

    #pragma unroll
    for (int k0 = 0; k0 < 512; k0 += 32) {
        bf16x8 a0 = *(const bf16x8*)(aptr0 + k0);
        bf16x8 a1 = *(const bf16x8*)(aptr1 + k0);
        bf16x8 b0 = *(const bf16x8*)(bptr0 + k0);
        bf16x8 b1 = *(const bf16x8*)(bptr1 + k0);
        acc00 = __builtin_amdgcn_mfma_f32_16x16x32_bf16(a0, b0, acc00, 0, 0, 0);
        acc01 = __builtin_amdgcn_mfma_f32_16x16x32_bf16(a0, b1, acc01, 0, 0, 0);
        acc10 = __builtin_amdgcn_mfma_f32_16x16x32_bf16(a1, b0, acc10, 0, 0, 0);
        acc11 = __builtin_amdgcn_mfma_f32_16x16x32_bf16(a1, b1, acc11, 0, 0, 0);
    }

    const int row = m0 + lq * 4;
    const int col = p0 + lr;
    #pragma unroll
    for (int r = 0; r < 4; ++r) {
        v[(size_t)(row + r) * 512 + col]           = acc00[r];
        v[(size_t)(row + r) * 512 + col + 16]      = acc01[r];
        v[(size_t)(row + 16 + r) * 512 + col]      = acc10[r];
        v[(size_t)(row + 16 + r) * 512 + col + 16] = acc11[r];
    }
}

// ---------------------------------------------------------------------------
// Kernel C (v5): out-side expansion with COALESCED y stores.
//   All prior variants (39-47us) stored per-thread-16-consecutive floats
//   (obase = t*16): each store instruction put lanes at 64B stride ->
//   16B-of-64B partial-sector writes -> ~1.6 TB/s effective (4x loss),
//   64MB/1.6TBps = 40us = the whole kernel time. Fix: hand w2 off through
//   LDS (w2s[k][a*16+b], stride-257 pad) and remap the y phase so store s
//   writes y[n*4096 + s*1024 + t*4]: lane-consecutive float4s, 1KB
//   contiguous per wave-instruction.
//   Decomposition of out = s*1024 + t*4 + q:
//     a = s*4 + (t>>6), b = (t>>2)&15, c = (t&3)*4 + q.
//   w1/w2 compute stages identical to proven R4 version.
// ---------------------------------------------------------------------------
__global__ __launch_bounds__(THREADS) void k_out_expand5(
    const float* __restrict__ v,
    const float* __restrict__ f0, const float* __restrict__ f1,
    const float* __restrict__ f2, const float* __restrict__ bias,
    float* __restrict__ y, int N)
{
    const int n = blockIdx.x;
    const int t = threadIdx.x;

    __shared__ float fs[256];         // f0 [0..128) | f1 [128..256)
    __shared__ float vs[512];
    __shared__ float w1s[128 * 9];    // [a*8+j][k], pad 9
    __shared__ float w2s[8 * 257];    // [k][a*16+b], pad 257 (conflict-free)

    if (t < 128) { fs[t] = f0[t]; fs[128 + t] = f1[t]; }
    if (t < 128) ((float4*)vs)[t] = ((const float4*)(v + (size_t)n*512))[t];

    // preload this thread's 4 f2 rows (c = (t&3)*4 + 0..3): 32 floats,
    // 8 float4 loads, static indices only (rule #20).
    float f2r[32];
    {
        const float4* fp = (const float4*)(f2 + ((t & 3) * 4) * 8);
        #pragma unroll
        for (int q8 = 0; q8 < 8; ++q8) {
            float4 ff = fp[q8];
            f2r[q8*4+0] = ff.x; f2r[q8*4+1] = ff.y;
            f2r[q8*4+2] = ff.z; f2r[q8*4+3] = ff.w;
        }
    }
    __syncthreads();

    // w1 stage: thread -> (a = t>>4, j = (t>>1)&7, h = t&1), k = 4h..4h+3
    {
        const int a = t >> 4, j = (t >> 1) & 7, h = t & 1;
        float fr[8];
        #pragma unroll
        for (int i = 0; i < 8; ++i) fr[i] = fs[a*8 + i];
        float a4[4] = {0.f, 0.f, 0.f, 0.f};
        #pragma unroll
        for (int i = 0; i < 8; ++i) {
            const int base = i*64 + j*8 + h*4;
            #pragma unroll
            for (int q = 0; q < 4; ++q)
                a4[q] = fmaf(vs[base + q], fr[i], a4[q]);
        }
        #pragma unroll
        for (int q = 0; q < 4; ++q) w1s[(a*8 + j)*9 + h*4 + q] = a4[q];
    }
    __syncthreads();

    // w2 stage: thread -> (a = t>>4, b = t&15); write w2s[k][t] (t == a*16+b)
    {
        const int a = t >> 4, b = t & 15;
        float fr[8];
        #pragma unroll
        for (int j = 0; j < 8; ++j) fr[j] = fs[128 + b*8 + j];
        float w2[8] = {0.f,0.f,0.f,0.f,0.f,0.f,0.f,0.f};
        #pragma unroll
        for (int j = 0; j < 8; ++j) {
            const int base = (a*8 + j)*9;
            const float fj = fr[j];
            #pragma unroll
            for (int k = 0; k < 8; ++k)
                w2[k] = fmaf(w1s[base + k], fj, w2[k]);
        }
        #pragma unroll
        for (int k = 0; k < 8; ++k) w2s[k*257 + t] = w2[k];
    }
    __syncthreads();

    // y stage: store s writes y[n*4096 + s*1024 + t*4 .. +4) — coalesced.
    //   needs w2[A=s*4+(t>>6)][B=(t>>2)&15][k] from LDS (b32, conflict-free)
    //   and f2r[q*8+k] (this thread's preloaded rows).
    {
        const int w = t >> 6;            // wave id
        const int B = (t >> 2) & 15;
        const float4* bias4 = (const float4*)bias;
        float4* y4 = (float4*)(y + (size_t)n * 4096);

        #pragma unroll
        for (int s = 0; s < 4; ++s) {
            const int AB = (s*4 + w) * 16 + B;
            float w2v[8];
            #pragma unroll
            for (int k = 0; k < 8; ++k) w2v[k] = w2s[k*257 + AB];

            float4 bb = bias4[s*256 + t];
            float r0 = bb.x, r1 = bb.y, r2 = bb.z, r3 = bb.w;
            #pragma unroll
            for (int k = 0; k < 8; ++k) {
                r0 = fmaf(w2v[k], f2r[0*8 + k], r0);
                r1 = fmaf(w2v[k], f2r[1*8 + k], r1);
                r2 = fmaf(w2v[k], f2r[2*8 + k], r2);
                r3 = fmaf(w2v[k], f2r[3*8 + k], r3);
            }
            y4[s*256 + t] = make_float4(r0, r1, r2, r3);
        }
    }
}

// ---------------------------------------------------------------------------
extern "C" void kernel_launch(void* const* d_in, const int* in_sizes, int n_in,
                              void* d_out, int out_size, void* d_ws, size_t ws_size,
                              hipStream_t stream)
{
    const float* x    = (const float*)d_in[0];
    const float* core = (const float*)d_in[1];
    const float* f0   = (const float*)d_in[2];
    const float* f1   = (const float*)d_in[3];
    const float* f2   = (const float*)d_in[4];
    const float* f3   = (const float*)d_in[5];
    const float* f4   = (const float*)d_in[6];
    const float* f5   = (const float*)d_in[7];
    const float* bias = (const float*)d_in[8];
    float* y = (float*)d_out;

    const int N = in_sizes[0] / 4096;

    // workspace: u3b bf16 [N,512] (4MB) | coreb bf16 [512,512] (0.5MB)
    //          | v fp32 [N,512] (8MB)
    unsigned short* u3b   = (unsigned short*)d_ws;
    unsigned short* coreb = u3b + (size_t)N * 512;
    float*          v     = (float*)(coreb + 512 * 512);

    k_in_contract<<<N, THREADS, 0, stream>>>(x, f3, f4, f5, u3b, N);
    k_convert_core<<<256, THREADS, 0, stream>>>(core, coreb);
    dim3 gb(N / 128, 512 / 32);
    k_core_gemm_mfma<<<gb, THREADS, 0, stream>>>(u3b, coreb, v, N);
    k_out_expand5<<<N, THREADS, 0, stream>>>(v, f0, f1, f2, bias, y, N);
}

// Round 9
// 153.322 us; speedup vs baseline: 1.1489x; 1.0531x over previous
//
#include <hip/hip_runtime.h>

#define THREADS 256

typedef __attribute__((ext_vector_type(8))) short bf16x8;
typedef __attribute__((ext_vector_type(4))) float f32x4;

// fp32 -> bf16 with round-to-nearest-even (matches HW convert)
__device__ inline unsigned short f2bf(float f) {
    union { float f; unsigned int u; } v; v.f = f;
    unsigned int r = v.u + 0x7fffu + ((v.u >> 16) & 1u);
    return (unsigned short)(r >> 16);
}

// LDS-only barrier: orders LDS producer/consumer WITHOUT draining vmcnt —
// global stores issued before it stay in flight (unlike __syncthreads,
// which the compiler precedes with s_waitcnt vmcnt(0)).
__device__ inline void lds_barrier() {
    asm volatile("s_waitcnt lgkmcnt(0)" ::: "memory");
    __builtin_amdgcn_s_barrier();
    __builtin_amdgcn_sched_barrier(0);
}

// ---------------------------------------------------------------------------
// Kernel A: in-side contraction  x[N,4096] -> u3b[N,512] (bf16)
//   (EXACT round-0 proven version, ~21 us. FROZEN.)
// ---------------------------------------------------------------------------
__global__ __launch_bounds__(THREADS) void k_in_contract(
    const float* __restrict__ x,
    const float* __restrict__ f3, const float* __restrict__ f4,
    const float* __restrict__ f5,
    unsigned short* __restrict__ u3b, int N)
{
    const int n = blockIdx.x;
    const int t = threadIdx.x;

    __shared__ float fs[256];        // f3 [0..128) | f4 [128..256)
    __shared__ float u1s[256 * 9];   // [de][n6], pad 9 -> 2-way max
    __shared__ float u2s[128 * 9];   // [d*8+m][n6], pad 9

    if (t < 128) { fs[t] = f3[t]; fs[128 + t] = f4[t]; }

    float xv[16];
    {
        const float4* xr = (const float4*)(x + (size_t)n * 4096 + t * 16);
        float4 a0 = xr[0], a1 = xr[1], a2 = xr[2], a3 = xr[3];
        xv[0]=a0.x; xv[1]=a0.y; xv[2]=a0.z; xv[3]=a0.w;
        xv[4]=a1.x; xv[5]=a1.y; xv[6]=a1.z; xv[7]=a1.w;
        xv[8]=a2.x; xv[9]=a2.y; xv[10]=a2.z; xv[11]=a2.w;
        xv[12]=a3.x; xv[13]=a3.y; xv[14]=a3.z; xv[15]=a3.w;
    }

    float acc8[8];
    #pragma unroll
    for (int q = 0; q < 8; ++q) acc8[q] = 0.f;
    #pragma unroll
    for (int f = 0; f < 16; ++f) {
        const float xf = xv[f];
        #pragma unroll
        for (int n6 = 0; n6 < 8; ++n6)
            acc8[n6] = fmaf(xf, f5[f*8 + n6], acc8[n6]);
    }
    __syncthreads();
    #pragma unroll
    for (int n6 = 0; n6 < 8; ++n6) u1s[t*9 + n6] = acc8[n6];
    __syncthreads();

    {
        const int d = t >> 4, m = (t >> 1) & 7, h = t & 1;
        float fr[16];
        #pragma unroll
        for (int e = 0; e < 16; ++e) fr[e] = fs[128 + e*8 + m];
        float a4[4] = {0.f, 0.f, 0.f, 0.f};
        #pragma unroll
        for (int e = 0; e < 16; ++e) {
            const int base = (d*16 + e)*9 + h*4;
            #pragma unroll
            for (int q = 0; q < 4; ++q)
                a4[q] = fmaf(u1s[base + q], fr[e], a4[q]);
        }
        #pragma unroll
        for (int q = 0; q < 4; ++q) u2s[(d*8 + m)*9 + h*4 + q] = a4[q];
    }
    __syncthreads();

    {
        const int l = t >> 5, m = (t >> 2) & 7, h = t & 3;
        float fr[16];
        #pragma unroll
        for (int d = 0; d < 16; ++d) fr[d] = fs[d*8 + l];
        float a2[2] = {0.f, 0.f};
        #pragma unroll
        for (int d = 0; d < 16; ++d) {
            const int base = (d*8 + m)*9 + h*2;
            a2[0] = fmaf(u2s[base],     fr[d], a2[0]);
            a2[1] = fmaf(u2s[base + 1], fr[d], a2[1]);
        }
        unsigned int pk = (unsigned int)f2bf(a2[0]) |
                          ((unsigned int)f2bf(a2[1]) << 16);
        ((unsigned int*)u3b)[(size_t)n * 256 + t] = pk;
    }
}

// ---------------------------------------------------------------------------
// core fp32 [512,512] -> bf16. (FROZEN)
// ---------------------------------------------------------------------------
__global__ __launch_bounds__(THREADS) void k_convert_core(
    const float* __restrict__ core, unsigned short* __restrict__ coreb)
{
    const int i = blockIdx.x * THREADS + threadIdx.x;
    float4 c = ((const float4*)core)[i];
    ushort4 o;
    o.x = f2bf(c.x); o.y = f2bf(c.y); o.z = f2bf(c.z); o.w = f2bf(c.w);
    ((ushort4*)coreb)[i] = o;
}

// ---------------------------------------------------------------------------
// Kernel B: MFMA GEMM (EXACT round-0 proven version, ~8.4 us. FROZEN.)
//   Wave tile 32x32 (2x2 of 16x16x32 bf16). Grid (32,16) = 512 blocks.
// ---------------------------------------------------------------------------
__global__ __launch_bounds__(THREADS) void k_core_gemm_mfma(
    const unsigned short* __restrict__ u3b,
    const unsigned short* __restrict__ coreb,
    float* __restrict__ v, int N)
{
    const int t    = threadIdx.x;
    const int lane = t & 63;
    const int wave = t >> 6;
    const int m0 = blockIdx.x * 128 + wave * 32;
    const int p0 = blockIdx.y * 32;
    const int lr = lane & 15;
    const int lq = lane >> 4;

    const unsigned short* aptr0 = u3b   + (size_t)(m0 + lr) * 512 + lq * 8;
    const unsigned short* aptr1 = aptr0 + 16 * 512;
    const unsigned short* bptr0 = coreb + (size_t)(p0 + lr) * 512 + lq * 8;
    const unsigned short* bptr1 = bptr0 + 16 * 512;

    f32x4 acc00 = {0.f,0.f,0.f,0.f}, acc01 = {0.f,0.f,0.f,0.f};
    f32x4 acc10 = {0.f,0.f,0.f,0.f}, acc11 = {0.f,0.f,0.f,0.f};

    #pragma unroll
    for (int k0 = 0; k0 < 512; k0 += 32) {
        bf16x8 a0 = *(const bf16x8*)(aptr0 + k0);
        bf16x8 a1 = *(const bf16x8*)(aptr1 + k0);
        bf16x8 b0 = *(const bf16x8*)(bptr0 + k0);
        bf16x8 b1 = *(const bf16x8*)(bptr1 + k0);
        acc00 = __builtin_amdgcn_mfma_f32_16x16x32_bf16(a0, b0, acc00, 0, 0, 0);
        acc01 = __builtin_amdgcn_mfma_f32_16x16x32_bf16(a0, b1, acc01, 0, 0, 0);
        acc10 = __builtin_amdgcn_mfma_f32_16x16x32_bf16(a1, b0, acc10, 0, 0, 0);
        acc11 = __builtin_amdgcn_mfma_f32_16x16x32_bf16(a1, b1, acc11, 0, 0, 0);
    }

    const int row = m0 + lq * 4;
    const int col = p0 + lr;
    #pragma unroll
    for (int r = 0; r < 4; ++r) {
        v[(size_t)(row + r) * 512 + col]           = acc00[r];
        v[(size_t)(row + r) * 512 + col + 16]      = acc01[r];
        v[(size_t)(row + 16 + r) * 512 + col]      = acc10[r];
        v[(size_t)(row + 16 + r) * 512 + col + 16] = acc11[r];
    }
}

// ---------------------------------------------------------------------------
// Kernel C (v6): 4 ROWS PER BLOCK, store-pipelined.
//   expand5's exact verified stages (coalesced y stores), restructured so
//   each block loops over 4 rows with:
//   - lds_barrier (lgkmcnt-only) instead of __syncthreads: y stores from
//     row r stay IN FLIGHT through rows r+1..r+3 (vmcnt never drained
//     in-loop). Theory: all prior variants were limited by store
//     duty-cycle — each wave stored only in a brief terminal burst.
//   - next row's v prefetched into registers during w1 (T14 split),
//     ds_written to vs after the w2 barrier.
//   - bias/f2 register-hoisted out of the loop (static indices, rule #20).
//   Grid N/4 = 1024 blocks; LDS ~16KB; ~90 VGPR -> ~5 blocks/CU resident.
// ---------------------------------------------------------------------------
__global__ __launch_bounds__(THREADS) void k_out_expand6(
    const float* __restrict__ v,
    const float* __restrict__ f0, const float* __restrict__ f1,
    const float* __restrict__ f2, const float* __restrict__ bias,
    float* __restrict__ y, int N)
{
    const int t  = threadIdx.x;
    const int r0 = blockIdx.x * 4;

    __shared__ float fs[256];         // f0 [0..128) | f1 [128..256)
    __shared__ float vs[512];
    __shared__ float w1s[128 * 9];    // [a*8+j][k], pad 9
    __shared__ float w2s[8 * 257];    // [k][a*16+b], pad 257

    if (t < 128) { fs[t] = f0[t]; fs[128 + t] = f1[t]; }
    // initial v row -> LDS
    if (t < 128) ((float4*)vs)[t] = ((const float4*)(v + (size_t)r0 * 512))[t];

    // hoisted per-thread constants (static indices only)
    float f2r[32];
    {
        const float4* fp = (const float4*)(f2 + ((t & 3) * 4) * 8);
        #pragma unroll
        for (int q8 = 0; q8 < 8; ++q8) {
            float4 ff = fp[q8];
            f2r[q8*4+0] = ff.x; f2r[q8*4+1] = ff.y;
            f2r[q8*4+2] = ff.z; f2r[q8*4+3] = ff.w;
        }
    }
    const float4* bias4 = (const float4*)bias;
    float4 bb0 = bias4[0*256 + t], bb1 = bias4[1*256 + t];
    float4 bb2 = bias4[2*256 + t], bb3 = bias4[3*256 + t];

    lds_barrier();   // fs + vs(row 0) visible

    const int a_ = t >> 4, j_ = (t >> 1) & 7, h_ = t & 1;   // w1 roles
    const int b_ = t & 15;                                   // w2 role (a==a_)
    const int w_ = t >> 6, B_ = (t >> 2) & 15;               // y roles

    float fr0[8], fr1[8];
    #pragma unroll
    for (int i = 0; i < 8; ++i) fr0[i] = fs[a_*8 + i];
    #pragma unroll
    for (int j = 0; j < 8; ++j) fr1[j] = fs[128 + b_*8 + j];

    #pragma unroll 1
    for (int rr = 0; rr < 4; ++rr) {
        const int n = r0 + rr;

        // prefetch next row's v into a register (issued before w1 compute)
        float4 vpf = make_float4(0.f, 0.f, 0.f, 0.f);
        if (rr < 3 && t < 128)
            vpf = ((const float4*)(v + (size_t)(n + 1) * 512))[t];

        // ---- w1 stage: reads vs, writes w1s ----
        {
            float a4[4] = {0.f, 0.f, 0.f, 0.f};
            #pragma unroll
            for (int i = 0; i < 8; ++i) {
                const int base = i*64 + j_*8 + h_*4;
                const float fi = fr0[i];
                #pragma unroll
                for (int q = 0; q < 4; ++q)
                    a4[q] = fmaf(vs[base + q], fi, a4[q]);
            }
            #pragma unroll
            for (int q = 0; q < 4; ++q) w1s[(a_*8 + j_)*9 + h_*4 + q] = a4[q];
        }
        lds_barrier();   // w1s visible; vs now free

        // ---- w2 stage: reads w1s, writes w2s[k][t] ----
        {
            float w2[8] = {0.f,0.f,0.f,0.f,0.f,0.f,0.f,0.f};
            #pragma unroll
            for (int j = 0; j < 8; ++j) {
                const int base = (a_*8 + j)*9;
                const float fj = fr1[j];
                #pragma unroll
                for (int k = 0; k < 8; ++k)
                    w2[k] = fmaf(w1s[base + k], fj, w2[k]);
            }
            #pragma unroll
            for (int k = 0; k < 8; ++k) w2s[k*257 + t] = w2[k];
        }
        // write next row's v into vs (vs free since previous barrier)
        if (rr < 3 && t < 128) ((float4*)vs)[t] = vpf;
        lds_barrier();   // w2s + new vs visible; w1s free

        // ---- y stage: coalesced stores, s covers 4 chunks of 1KB/wave ----
        {
            float4* y4 = (float4*)(y + (size_t)n * 4096);
            #pragma unroll
            for (int s = 0; s < 4; ++s) {
                const int AB = (s*4 + w_) * 16 + B_;
                float w2v[8];
                #pragma unroll
                for (int k = 0; k < 8; ++k) w2v[k] = w2s[k*257 + AB];

                float4 bb = (s == 0) ? bb0 : (s == 1) ? bb1
                          : (s == 2) ? bb2 : bb3;
                float rv0 = bb.x, rv1 = bb.y, rv2 = bb.z, rv3 = bb.w;
                #pragma unroll
                for (int k = 0; k < 8; ++k) {
                    rv0 = fmaf(w2v[k], f2r[0*8 + k], rv0);
                    rv1 = fmaf(w2v[k], f2r[1*8 + k], rv1);
                    rv2 = fmaf(w2v[k], f2r[2*8 + k], rv2);
                    rv3 = fmaf(w2v[k], f2r[3*8 + k], rv3);
                }
                y4[s*256 + t] = make_float4(rv0, rv1, rv2, rv3);
            }
        }
        lds_barrier();   // w2s free for next row (stores NOT drained)
    }
}

// ---------------------------------------------------------------------------
extern "C" void kernel_launch(void* const* d_in, const int* in_sizes, int n_in,
                              void* d_out, int out_size, void* d_ws, size_t ws_size,
                              hipStream_t stream)
{
    const float* x    = (const float*)d_in[0];
    const float* core = (const float*)d_in[1];
    const float* f0   = (const float*)d_in[2];
    const float* f1   = (const float*)d_in[3];
    const float* f2   = (const float*)d_in[4];
    const float* f3   = (const float*)d_in[5];
    const float* f4   = (const float*)d_in[6];
    const float* f5   = (const float*)d_in[7];
    const float* bias = (const float*)d_in[8];
    float* y = (float*)d_out;

    const int N = in_sizes[0] / 4096;

    // workspace: u3b bf16 [N,512] (4MB) | coreb bf16 [512,512] (0.5MB)
    //          | v fp32 [N,512] (8MB)
    unsigned short* u3b   = (unsigned short*)d_ws;
    unsigned short* coreb = u3b + (size_t)N * 512;
    float*          v     = (float*)(coreb + 512 * 512);

    k_in_contract<<<N, THREADS, 0, stream>>>(x, f3, f4, f5, u3b, N);
    k_convert_core<<<256, THREADS, 0, stream>>>(core, coreb);
    dim3 gb(N / 128, 512 / 32);
    k_core_gemm_mfma<<<gb, THREADS, 0, stream>>>(u3b, coreb, v, N);
    k_out_expand6<<<N / 4, THREADS, 0, stream>>>(v, f0, f1, f2, bias, y, N);
}